// Round 16
// baseline (218.667 us; speedup 1.0000x reference)
//
#include <hip/hip_runtime.h>

#define SEQ 2048
#define DMODEL 1024
#define NH 16
#define DH 64

typedef __attribute__((ext_vector_type(8))) short bf16x8;
typedef __attribute__((ext_vector_type(4))) short bf16x4;
typedef __attribute__((ext_vector_type(4))) float floatx4;
typedef __attribute__((ext_vector_type(4))) unsigned short u16x4;
typedef unsigned short u16;
typedef unsigned int u32;

typedef const void __attribute__((address_space(1)))* as1cvp;
typedef void __attribute__((address_space(3)))* as3vp;

__device__ __forceinline__ void glds16(const void* g, void* l) {
    __builtin_amdgcn_global_load_lds((as1cvp)g, (as3vp)l, 16, 0, 0);
}

// f32->bf16 round-half-up: u + 0x8000, take hi16. Same 0.5-ulp worst case as
// RNE (only exact-tie direction differs -> unbiased for continuous data).
__device__ __forceinline__ u16 f2bf(float f) {
    union { u32 u; float f; } v; v.f = f;
    return (u16)((v.u + 0x8000u) >> 16);
}

// packed f32->2xbf16 half-up: 2 adds + 1 v_perm_b32 (hi16 of each)
__device__ __forceinline__ u32 pk2(float a, float b) {
    union { u32 u; float f; } x, y; x.f = a; y.f = b;
    u32 xr = x.u + 0x8000u, yr = y.u + 0x8000u;
#if __has_builtin(__builtin_amdgcn_perm)
    return __builtin_amdgcn_perm(yr, xr, 0x07060302u);
#else
    return (xr >> 16) | (yr & 0xffff0000u);
#endif
}

// raw v_exp_f32 (= exp2); log2e folded into QSCALE so scores are log2-domain.
__device__ __forceinline__ float ex2(float x) {
#if __has_builtin(__builtin_amdgcn_exp2f)
    return __builtin_amdgcn_exp2f(x);
#else
    float r; asm("v_exp_f32 %0, %1" : "=v"(r) : "v"(x)); return r;
#endif
}

__device__ __forceinline__ floatx4 mfma32(bf16x8 a, bf16x8 b, floatx4 c) {
    return __builtin_amdgcn_mfma_f32_16x16x32_bf16(a, b, c, 0, 0, 0);
}

__device__ __forceinline__ uint4 cvt8(const float* __restrict__ p) {
    float4 a = *(const float4*)p;
    float4 b = *(const float4*)(p + 4);
    uint4 q;
    q.x = pk2(a.x, a.y); q.y = pk2(a.z, a.w);
    q.z = pk2(b.x, b.y); q.w = pk2(b.z, b.w);
    return q;
}

// q pre-scale: 1/sqrt(Dh) * log2(e) -> scores are log2-domain, exp via v_exp_f32
#define QSCALE 0.18033688011112042f

// ---------------- convert Q,K,V + 4 weights to bf16 once ----------------
__global__ __launch_bounds__(256) void cvt_all(
    const float* __restrict__ Q, const float* __restrict__ K, const float* __restrict__ V,
    const float* __restrict__ W0, const float* __restrict__ W1,
    const float* __restrict__ W2, const float* __restrict__ W3,
    u16* __restrict__ Qb, u16* __restrict__ Kb, u16* __restrict__ Vb,
    u16* __restrict__ Wb)
{
    const int y = blockIdx.y;
    const float* src; u16* dst;
    if (y == 0)      { src = Q;  dst = Qb; }
    else if (y == 1) { src = K;  dst = Kb; }
    else if (y == 2) { src = V;  dst = Vb; }
    else {
        if (blockIdx.x >= 512) return;
        src = (y == 3) ? W0 : (y == 4) ? W1 : (y == 5) ? W2 : W3;
        dst = Wb + (size_t)(y - 3) * 1048576;
    }
    size_t i = ((size_t)blockIdx.x * 256 + threadIdx.x) * 8;
    *(uint4*)(dst + i) = cvt8(src + i);
}

__global__ __launch_bounds__(256) void cvt_w(
    const float* __restrict__ W0, const float* __restrict__ W1,
    const float* __restrict__ W2, const float* __restrict__ W3,
    u16* __restrict__ out)
{
    const float* src = (blockIdx.y == 0) ? W0 : (blockIdx.y == 1) ? W1
                     : (blockIdx.y == 2) ? W2 : W3;
    size_t i = ((size_t)blockIdx.x * 256 + threadIdx.x) * 8;
    *(uint4*)(out + (size_t)blockIdx.y * 1048576 + i) = cvt8(src + i);
}

// shared epilogue store for QKV projections (z<2: scalar, z=2: vectorized 8B)
__device__ __forceinline__ void qkv_store(
    int z, u16* __restrict__ outp, int rowg, int col, floatx4 a4, float bv, float sc)
{
    union { u32 w[2]; u16 h[4]; u16x4 v4; } pk;
    pk.w[0] = pk2((a4[0] + bv) * sc, (a4[1] + bv) * sc);
    pk.w[1] = pk2((a4[2] + bv) * sc, (a4[3] + bv) * sc);
    int b = rowg >> 11, s = rowg & 2047, h = col >> 6, d = col & 63;
    if (z < 2) {
#pragma unroll
        for (int r = 0; r < 4; r++)
            outp[((size_t)(b * NH + h) * SEQ + s + r) * DH + d] = pk.h[r];
    } else {
        *(u16x4*)(outp + ((size_t)(b * NH + h) * DH + d) * SEQ + s) = pk.v4;
    }
}

// ---------------- QKV projection: 3-buffer LDS pipeline, counted vmcnt ----------------
// XCD swizzle (T1): grid 768 blocks; each XCD gets 96 contiguous logical
// blocks (~12 A-panels x 8 bn in one z): A 3MB + W 2MB ~ L2-resident.
__global__ __launch_bounds__(256) void gemm_qkv_bb(
    const u16* __restrict__ Qb, const u16* __restrict__ Kb, const u16* __restrict__ Vb,
    const u16* __restrict__ Wb,
    const float* __restrict__ b0, const float* __restrict__ b1, const float* __restrict__ b2,
    u16* __restrict__ qo, u16* __restrict__ ko, u16* __restrict__ vto)
{
    __shared__ __align__(16) u16 As[3][4096];
    __shared__ __align__(16) u16 Bs[3][4096];
    const int tid = threadIdx.x, l = tid & 63, w = tid >> 6;
    const int lm = l & 15, quad = l >> 4;
    const int wr = (w >> 1) * 64, wc = (w & 1) * 64;
    const int orig = blockIdx.x + 8 * blockIdx.y + 256 * blockIdx.z;  // 0..767
    const int swz  = (orig & 7) * 96 + (orig >> 3);                   // bijective
    const int z    = swz >> 8;           // 0..2
    const int rem  = swz & 255;
    const int bm = (rem >> 3) * 128, bn = (rem & 7) * 128;
    const u16* A      = (z == 0) ? Qb : (z == 1) ? Kb : Vb;
    const u16* W      = Wb + (size_t)z * 1048576;
    const float* bias = (z == 0) ? b0 : (z == 1) ? b1 : b2;

    const int srow = tid >> 2, scol = (tid & 3) * 8;

    floatx4 acc[4][4];
#pragma unroll
    for (int i = 0; i < 4; i++)
#pragma unroll
        for (int j = 0; j < 4; j++) acc[i][j] = (floatx4){0.f, 0.f, 0.f, 0.f};

#define QKV_STAGE(I, NB) do { \
        const int kt_ = (I) * 32; \
        glds16(A + (size_t)(bm + srow) * DMODEL + kt_ + scol, As[NB] + w * 512); \
        glds16(A + (size_t)(bm + 64 + srow) * DMODEL + kt_ + scol, As[NB] + 2048 + w * 512); \
        glds16(W + (size_t)(bn + srow) * DMODEL + kt_ + scol, Bs[NB] + w * 512); \
        glds16(W + (size_t)(bn + 64 + srow) * DMODEL + kt_ + scol, Bs[NB] + 2048 + w * 512); \
    } while (0)

    QKV_STAGE(0, 0);
    QKV_STAGE(1, 1);
    asm volatile("s_waitcnt vmcnt(4)" ::: "memory");   // tile 0 complete
    __builtin_amdgcn_s_barrier();

    int cur = 0, nx = 2;
    for (int i = 0; i < 32; i++) {
        bf16x8 af[4], bfr[4];
#pragma unroll
        for (int mi = 0; mi < 4; mi++)
            af[mi] = *(const bf16x8*)(As[cur] + (wr + mi * 16 + lm) * 32 + quad * 8);
#pragma unroll
        for (int ni = 0; ni < 4; ni++)
            bfr[ni] = *(const bf16x8*)(Bs[cur] + (wc + ni * 16 + lm) * 32 + quad * 8);
#pragma unroll
        for (int mi = 0; mi < 4; mi++)
#pragma unroll
            for (int ni = 0; ni < 4; ni++)
                acc[mi][ni] = __builtin_amdgcn_mfma_f32_16x16x32_bf16(
                    af[mi], bfr[ni], acc[mi][ni], 0, 0, 0);

        if (i + 2 < 32) {
            QKV_STAGE(i + 2, nx);
            asm volatile("s_waitcnt vmcnt(4)" ::: "memory");  // tile i+1 done
            __builtin_amdgcn_s_barrier();
        } else if (i + 1 < 32) {
            asm volatile("s_waitcnt vmcnt(0)" ::: "memory");
            __builtin_amdgcn_s_barrier();
        }
        cur = (cur == 2) ? 0 : cur + 1;
        nx  = (nx == 2) ? 0 : nx + 1;
    }
#undef QKV_STAGE

    const float sc = (z == 0) ? QSCALE : 1.0f;
    u16* outp = (z == 0) ? qo : (z == 1) ? ko : vto;
#pragma unroll
    for (int ni = 0; ni < 4; ni++) {
        int col = bn + wc + ni * 16 + lm;
        float bv = bias[col];
#pragma unroll
        for (int mi = 0; mi < 4; mi++)
            qkv_store(z, outp, bm + wr + mi * 16 + quad * 4, col, acc[mi][ni], bv, sc);
    }
}

// ---------------- legacy QKV (A f32 converted in staging; fallback paths) ----------------
template<bool WBF>
__global__ __launch_bounds__(256) void gemm_qkv(
    const float* __restrict__ Qf, const float* __restrict__ Kf, const float* __restrict__ Vf,
    const void* __restrict__ W0, const void* __restrict__ W1, const void* __restrict__ W2,
    const float* __restrict__ b0, const float* __restrict__ b1, const float* __restrict__ b2,
    u16* __restrict__ qo, u16* __restrict__ ko, u16* __restrict__ vto)
{
    __shared__ __align__(16) u16 As[128 * 32];
    __shared__ __align__(16) u16 Bs[128 * 32];
    const int tid = threadIdx.x, l = tid & 63, w = tid >> 6;
    const int lm = l & 15, quad = l >> 4;
    const int wr = (w >> 1) * 64, wc = (w & 1) * 64;
    const int bm = blockIdx.y * 128, bn = blockIdx.x * 128;
    const int z = blockIdx.z;
    const float* A    = (z == 0) ? Qf : (z == 1) ? Kf : Vf;
    const void* Wp    = (z == 0) ? W0 : (z == 1) ? W1 : W2;
    const float* bias = (z == 0) ? b0 : (z == 1) ? b1 : b2;

    floatx4 acc[4][4];
#pragma unroll
    for (int i = 0; i < 4; i++)
#pragma unroll
        for (int j = 0; j < 4; j++) acc[i][j] = (floatx4){0.f, 0.f, 0.f, 0.f};

    for (int kt = 0; kt < DMODEL; kt += 32) {
        __syncthreads();
#pragma unroll
        for (int j = 0; j < 2; j++) {
            int ch = j * 256 + tid, row = ch >> 2, c = ch & 3;
            *(uint4*)(As + ch * 8) = cvt8(A + (size_t)(bm + row) * DMODEL + kt + c * 8);
        }
        if (WBF) {
            const u16* Wc = (const u16*)Wp;
            glds16(Wc + (size_t)(bn + (tid >> 2)) * DMODEL + kt + (tid & 3) * 8, Bs + w * 512);
            glds16(Wc + (size_t)(bn + 64 + (tid >> 2)) * DMODEL + kt + (tid & 3) * 8, Bs + 2048 + w * 512);
        } else {
            const float* Wf = (const float*)Wp;
#pragma unroll
            for (int j = 0; j < 2; j++) {
                int ch = j * 256 + tid, row = ch >> 2, c = ch & 3;
                *(uint4*)(Bs + ch * 8) = cvt8(Wf + (size_t)(bn + row) * DMODEL + kt + c * 8);
            }
        }
        __syncthreads();

        bf16x8 af[4], bfr[4];
#pragma unroll
        for (int mi = 0; mi < 4; mi++)
            af[mi] = *(const bf16x8*)(As + (wr + mi * 16 + lm) * 32 + quad * 8);
#pragma unroll
        for (int ni = 0; ni < 4; ni++)
            bfr[ni] = *(const bf16x8*)(Bs + (wc + ni * 16 + lm) * 32 + quad * 8);
#pragma unroll
        for (int mi = 0; mi < 4; mi++)
#pragma unroll
            for (int ni = 0; ni < 4; ni++)
                acc[mi][ni] = __builtin_amdgcn_mfma_f32_16x16x32_bf16(
                    af[mi], bfr[ni], acc[mi][ni], 0, 0, 0);
    }

    const float sc = (z == 0) ? QSCALE : 1.0f;
    u16* outp = (z == 0) ? qo : (z == 1) ? ko : vto;
#pragma unroll
    for (int ni = 0; ni < 4; ni++) {
        int col = bn + wc + ni * 16 + lm;
        float bv = bias[col];
#pragma unroll
        for (int mi = 0; mi < 4; mi++)
            qkv_store(z, outp, bm + wr + mi * 16 + quad * 4, col, acc[mi][ni], bv, sc);
    }
}

// ---------------- O-projection (bf16 W): 3-buffer pipeline, counted vmcnt ----------------
// XCD swizzle (T1): 512 blocks; each XCD owns 64 contiguous logical blocks.
__global__ __launch_bounds__(256) void gemm_o_p(
    const u16* __restrict__ A, const u16* __restrict__ W,
    const float* __restrict__ bias, float* __restrict__ out)
{
    __shared__ __align__(16) u16 As[3][4096];
    __shared__ __align__(16) u16 Bs[3][2048];
    const int tid = threadIdx.x, l = tid & 63, w = tid >> 6;
    const int lm = l & 15, quad = l >> 4;
    const int orig = blockIdx.x + 16 * blockIdx.y;          // 0..511
    const int swz  = (orig & 7) * 64 + (orig >> 3);         // bijective
    const int bm = (swz >> 4) * 128, bn = (swz & 15) * 64;

    floatx4 acc[2][4];
#pragma unroll
    for (int i = 0; i < 2; i++)
#pragma unroll
        for (int j = 0; j < 4; j++) acc[i][j] = (floatx4){0.f, 0.f, 0.f, 0.f};

#define O_STAGE(I, NB) do { \
        const int kt_ = (I) * 32; \
        glds16(A + (size_t)(bm + (tid >> 2)) * DMODEL + kt_ + (tid & 3) * 8, As[NB] + w * 512); \
        glds16(A + (size_t)(bm + 64 + (tid >> 2)) * DMODEL + kt_ + (tid & 3) * 8, As[NB] + 2048 + w * 512); \
        glds16(W + (size_t)(bn + (tid >> 2)) * DMODEL + kt_ + (tid & 3) * 8, Bs[NB] + w * 512); \
    } while (0)

    O_STAGE(0, 0);
    O_STAGE(1, 1);
    asm volatile("s_waitcnt vmcnt(3)" ::: "memory");
    __builtin_amdgcn_s_barrier();

    int cur = 0, nx = 2;
    for (int i = 0; i < 32; i++) {
        bf16x8 af[2], bfr[4];
#pragma unroll
        for (int mi = 0; mi < 2; mi++)
            af[mi] = *(const bf16x8*)(As[cur] + (w * 32 + mi * 16 + lm) * 32 + quad * 8);
#pragma unroll
        for (int ni = 0; ni < 4; ni++)
            bfr[ni] = *(const bf16x8*)(Bs[cur] + (ni * 16 + lm) * 32 + quad * 8);
#pragma unroll
        for (int mi = 0; mi < 2; mi++)
#pragma unroll
            for (int ni = 0; ni < 4; ni++)
                acc[mi][ni] = __builtin_amdgcn_mfma_f32_16x16x32_bf16(
                    af[mi], bfr[ni], acc[mi][ni], 0, 0, 0);

        if (i + 2 < 32) {
            O_STAGE(i + 2, nx);
            asm volatile("s_waitcnt vmcnt(3)" ::: "memory");
            __builtin_amdgcn_s_barrier();
        } else if (i + 1 < 32) {
            asm volatile("s_waitcnt vmcnt(0)" ::: "memory");
            __builtin_amdgcn_s_barrier();
        }
        cur = (cur == 2) ? 0 : cur + 1;
        nx  = (nx == 2) ? 0 : nx + 1;
    }
#undef O_STAGE

#pragma unroll
    for (int ni = 0; ni < 4; ni++) {
        int col = bn + ni * 16 + lm;
        float bv = bias[col];
#pragma unroll
        for (int mi = 0; mi < 2; mi++) {
#pragma unroll
            for (int r = 0; r < 4; r++) {
                int rowg = bm + w * 32 + mi * 16 + quad * 4 + r;
                out[(size_t)rowg * DMODEL + col] = acc[mi][ni][r] + bv;
            }
        }
    }
}

// ---------------- legacy O-projection (f32 W fallback) ----------------
template<bool WBF>
__global__ __launch_bounds__(256) void gemm_o(
    const u16* __restrict__ A, const void* __restrict__ Wp,
    const float* __restrict__ bias, float* __restrict__ out)
{
    __shared__ __align__(16) u16 As[128 * 32];
    __shared__ __align__(16) u16 Bs[64 * 32];
    const int tid = threadIdx.x, l = tid & 63, w = tid >> 6;
    const int lm = l & 15, quad = l >> 4;
    const int bm = blockIdx.y * 128, bn = blockIdx.x * 64;

    floatx4 acc[2][4];
#pragma unroll
    for (int i = 0; i < 2; i++)
#pragma unroll
        for (int j = 0; j < 4; j++) acc[i][j] = (floatx4){0.f, 0.f, 0.f, 0.f};

    for (int kt = 0; kt < DMODEL; kt += 32) {
        __syncthreads();
        glds16(A + (size_t)(bm + (tid >> 2)) * DMODEL + kt + (tid & 3) * 8, As + w * 512);
        glds16(A + (size_t)(bm + 64 + (tid >> 2)) * DMODEL + kt + (tid & 3) * 8, As + 2048 + w * 512);
        if (WBF) {
            glds16((const u16*)Wp + (size_t)(bn + (tid >> 2)) * DMODEL + kt + (tid & 3) * 8, Bs + w * 512);
        } else {
            *(uint4*)(Bs + tid * 8) =
                cvt8((const float*)Wp + (size_t)(bn + (tid >> 2)) * DMODEL + kt + (tid & 3) * 8);
        }
        __syncthreads();

        bf16x8 af[2], bfr[4];
#pragma unroll
        for (int mi = 0; mi < 2; mi++)
            af[mi] = *(const bf16x8*)(As + (w * 32 + mi * 16 + lm) * 32 + quad * 8);
#pragma unroll
        for (int ni = 0; ni < 4; ni++)
            bfr[ni] = *(const bf16x8*)(Bs + (ni * 16 + lm) * 32 + quad * 8);
#pragma unroll
        for (int mi = 0; mi < 2; mi++)
#pragma unroll
            for (int ni = 0; ni < 4; ni++)
                acc[mi][ni] = __builtin_amdgcn_mfma_f32_16x16x32_bf16(
                    af[mi], bfr[ni], acc[mi][ni], 0, 0, 0);
    }

#pragma unroll
    for (int ni = 0; ni < 4; ni++) {
        int col = bn + ni * 16 + lm;
        float bv = bias[col];
#pragma unroll
        for (int mi = 0; mi < 2; mi++) {
#pragma unroll
            for (int r = 0; r < 4; r++) {
                int rowg = bm + w * 32 + mi * 16 + quad * 4 + r;
                out[(size_t)rowg * DMODEL + col] = acc[mi][ni][r] + bv;
            }
        }
    }
}

// ---------------- Flash attention v16: v15 + deferred-PV (T15) ----------------
// r15: 4 waves/SIMD reached MFMA 34 + VALU 39 = 73%; residual is the per-wave
// pack->PV serial chain. Deferred-PV: iter t runs {QK(t) || PV(t-1) [V from
// buf cur^1] || exp(t)->pbmNew} -> barrier#1 (fences V(t-1) reads) ->
// vmcnt(0)+WRBUF(t+1)->cur^1+LOADT(t+2) -> lgkm0 -> barrier#2. PV(t-1)
// depends only on last-iter state -> issues immediately; exp hides under it.
// +16 VGPR (second pbm), V stays in LDS (no vr regs -> no r5-style spill).
// pbm double-buffered via 2x-unrolled loop (static indexing, rule #20).
// Keeps: full-rate PV via permuted-K, no-max log2 softmax, l-via-ones,
// T1 XCD swizzle, padded merge epilogue.
#define SP 72
#define TS (64 * SP)          // one K or V tile in u16
#define BUFSZ (4 * TS)        // [K0][K1][V0][V1]
__global__ __launch_bounds__(512, 2) void attn_kernel(
    const u16* __restrict__ q, const u16* __restrict__ k,
    const u16* __restrict__ vt, u16* __restrict__ out)
{
    __shared__ __align__(16) u16 smem[2 * BUFSZ];   // 73728 B
    const int tid = threadIdx.x, l = tid & 63, w = tid >> 6;   // w in 0..7
    const int lm = l & 15, quad = l >> 4;
    // XCD-aware swizzle (T1): each XCD owns 64 contiguous logical blocks.
    const int orig = blockIdx.x + 16 * blockIdx.y;          // 0..511
    const int swz  = (orig & 7) * 64 + (orig >> 3);         // bijective
    const int qt = swz & 15, bh = swz >> 4;
    const int b = bh >> 4, h = bh & 15;
    const int rg = w & 3, half = w >> 2;

    bf16x8 qf[2][2];
#pragma unroll
    for (int nt = 0; nt < 2; nt++) {
        int row = qt * 128 + rg * 32 + nt * 16 + lm;
        const u16* qp = q + ((size_t)bh * SEQ + row) * DH;
        qf[nt][0] = *(const bf16x8*)(qp + quad * 8);
        qf[nt][1] = *(const bf16x8*)(qp + 32 + quad * 8);
    }

    floatx4 O[4][2];
#pragma unroll
    for (int dt = 0; dt < 4; dt++)
#pragma unroll
        for (int nt = 0; nt < 2; nt++) O[dt][nt] = (floatx4){0.f, 0.f, 0.f, 0.f};
    floatx4 Ol[2] = {(floatx4){0.f,0.f,0.f,0.f}, (floatx4){0.f,0.f,0.f,0.f}};
    bf16x8 pbmA[2][2], pbmB[2][2];

    const bf16x8 ones8 = {(short)0x3F80, (short)0x3F80, (short)0x3F80, (short)0x3F80,
                          (short)0x3F80, (short)0x3F80, (short)0x3F80, (short)0x3F80};

    // staging: 512 threads; K: key srow = tid>>3 (0..63), chunk sc = tid&7
    const int srow = tid >> 3, sc = tid & 7;
    // permuted K row: key srow = p*32+q*8+s*4+r -> row p*32+s*16+q*4+r
    const int prow = (srow & 32) | ((srow & 4) << 2) | ((srow & 24) >> 1) | (srow & 3);
    const u16* kbase = k + (size_t)bh * SEQ * DH;
    const u16* vbase = vt + (size_t)bh * DH * SEQ;

    uint4 kA, kB, vA, vB;
#define LOADT(T) do { \
        kA = *(const uint4*)(kbase + (size_t)((T) * 64 + srow) * DH + sc * 8); \
        kB = *(const uint4*)(kbase + (size_t)(1024 + (T) * 64 + srow) * DH + sc * 8); \
        vA = *(const uint4*)(vbase + (size_t)srow * SEQ + (T) * 64 + sc * 8); \
        vB = *(const uint4*)(vbase + (size_t)srow * SEQ + 1024 + (T) * 64 + sc * 8); \
    } while (0)
#define WRBUF(BUF) do { \
        u16* K0 = smem + (BUF) * BUFSZ; \
        u16* K1 = K0 + TS; \
        u16* V0 = K0 + 2 * TS; \
        u16* V1 = K0 + 3 * TS; \
        *(uint4*)(K0 + prow * SP + sc * 8) = kA; \
        *(uint4*)(K1 + prow * SP + sc * 8) = kB; \
        *(uint4*)(V0 + srow * SP + sc * 8) = vA; \
        *(uint4*)(V1 + srow * SP + sc * 8) = vB; \
    } while (0)

    // QK(T) + exp -> PBNEW (reads K of buf T&1)
#define QKEXP(T, PBNEW) do { \
        const u16* Kh_ = smem + ((T) & 1) * BUFSZ + half * TS; \
        _Pragma("unroll") \
        for (int p = 0; p < 2; p++) { \
            floatx4 Sc0[2], Sc1[2]; \
            __builtin_amdgcn_s_setprio(1); \
            _Pragma("unroll") \
            for (int s = 0; s < 2; s++) { \
                const int sub = p * 2 + s; \
                bf16x8 ka0 = *(const bf16x8*)(Kh_ + (sub * 16 + lm) * SP + quad * 8); \
                bf16x8 ka1 = *(const bf16x8*)(Kh_ + (sub * 16 + lm) * SP + 32 + quad * 8); \
                _Pragma("unroll") \
                for (int nt = 0; nt < 2; nt++) { \
                    floatx4 c = (floatx4){0.f, 0.f, 0.f, 0.f}; \
                    c = mfma32(ka0, qf[nt][0], c); \
                    c = mfma32(ka1, qf[nt][1], c); \
                    if (s == 0) Sc0[nt] = c; else Sc1[nt] = c; \
                } \
            } \
            __builtin_amdgcn_s_setprio(0); \
            _Pragma("unroll") \
            for (int nt = 0; nt < 2; nt++) { \
                floatx4 sa = Sc0[nt], sb = Sc1[nt]; \
                _Pragma("unroll") \
                for (int r = 0; r < 4; r++) { sa[r] = ex2(sa[r]); sb[r] = ex2(sb[r]); } \
                union { u32 w4[4]; bf16x8 v; } pku; \
                pku.w4[0] = pk2(sa[0], sa[1]); \
                pku.w4[1] = pk2(sa[2], sa[3]); \
                pku.w4[2] = pk2(sb[0], sb[1]); \
                pku.w4[3] = pk2(sb[2], sb[3]); \
                PBNEW[p][nt] = pku.v; \
            } \
        } \
    } while (0)

    // PV(T) + l-sum with PBOLD (reads V of buf T&1)
#define PVL(T, PBOLD) do { \
        const u16* Vh_ = smem + ((T) & 1) * BUFSZ + (2 + half) * TS; \
        __builtin_amdgcn_s_setprio(1); \
        _Pragma("unroll") \
        for (int nt = 0; nt < 2; nt++) { \
            Ol[nt] = mfma32(ones8, PBOLD[0][nt], Ol[nt]); \
            Ol[nt] = mfma32(ones8, PBOLD[1][nt], Ol[nt]); \
        } \
        _Pragma("unroll") \
        for (int dt = 0; dt < 4; dt++) { \
            bf16x8 va0 = *(const bf16x8*)(Vh_ + (dt * 16 + lm) * SP + quad * 8); \
            bf16x8 va1 = *(const bf16x8*)(Vh_ + (dt * 16 + lm) * SP + 32 + quad * 8); \
            _Pragma("unroll") \
            for (int nt = 0; nt < 2; nt++) { \
                O[dt][nt] = mfma32(va0, PBOLD[0][nt], O[dt][nt]); \
                O[dt][nt] = mfma32(va1, PBOLD[1][nt], O[dt][nt]); \
            } \
        } \
        __builtin_amdgcn_s_setprio(0); \
    } while (0)

    // iter T (1..15): QK(T) || PV(T-1) || exp -> barrier -> stage(T+1) -> barrier
#define AITER(T, PBOLD, PBNEW) do { \
        QKEXP(T, PBNEW); \
        PVL((T) - 1, PBOLD); \
        __builtin_amdgcn_s_barrier(); /* all V(T-1) reads done */ \
        if ((T) < 15) { \
            asm volatile("s_waitcnt vmcnt(0)" ::: "memory"); \
            WRBUF(((T) + 1) & 1); \
            if ((T) < 14) LOADT((T) + 2); \
        } \
        asm volatile("s_waitcnt lgkmcnt(0)" ::: "memory"); \
        __builtin_amdgcn_s_barrier(); \
    } while (0)

    LOADT(0);
    WRBUF(0);
    LOADT(1);
    asm volatile("s_waitcnt lgkmcnt(0)" ::: "memory");
    __builtin_amdgcn_s_barrier();

    // t = 0: QK only (no PV); WRBUF(1) touches buf1 which nobody reads yet
    QKEXP(0, pbmA);
    asm volatile("s_waitcnt vmcnt(0)" ::: "memory");
    WRBUF(1);
    LOADT(2);
    asm volatile("s_waitcnt lgkmcnt(0)" ::: "memory");
    __builtin_amdgcn_s_barrier();

    for (int td = 0; td < 7; td++) {
        AITER(2 * td + 1, pbmA, pbmB);
        AITER(2 * td + 2, pbmB, pbmA);
    }
    AITER(15, pbmA, pbmB);
    // post-loop: PV(15) with pbmB, V in buf 1 (not overwritten after)
    PVL(15, pbmB);
#undef AITER
#undef QKEXP
#undef PVL
#undef LOADT
#undef WRBUF

    __syncthreads();
    // ---- in-block merge of the two key-halves through LDS (f32) ----
    // no-max: O = (O_A + O_B) / (l_A + l_B). Stride 36 floats.
    float* obuf  = (float*)smem;           // [4 rg][64 lane][36] = 36864B
    float* mlbuf = (float*)smem + 9216;    // [4 rg][64 lane][2]  =  2048B
    if (half == 1) {
        float* ob = obuf + (rg * 64 + l) * 36;
        float* ml = mlbuf + (rg * 64 + l) * 2;
#pragma unroll
        for (int nt = 0; nt < 2; nt++) {
#pragma unroll
            for (int dt = 0; dt < 4; dt++)
                *(floatx4*)(ob + nt * 16 + dt * 4) = O[dt][nt];
            ml[nt] = Ol[nt][0];
        }
    }
    __syncthreads();
    if (half == 0) {
        float* ob = obuf + (rg * 64 + l) * 36;
        float* ml = mlbuf + (rg * 64 + l) * 2;
#pragma unroll
        for (int nt = 0; nt < 2; nt++) {
            float lB = ml[nt];
            float inv = 1.0f / (Ol[nt][0] + lB);
            int s = qt * 128 + rg * 32 + nt * 16 + lm;
            u16* op = out + ((size_t)b * SEQ + s) * DMODEL + h * DH;
#pragma unroll
            for (int dt = 0; dt < 4; dt++) {
                floatx4 Ob = *(const floatx4*)(ob + nt * 16 + dt * 4);
                union { u32 w2[2]; u16x4 v; } pku;
                pku.w2[0] = pk2((O[dt][nt][0] + Ob[0]) * inv,
                                (O[dt][nt][1] + Ob[1]) * inv);
                pku.w2[1] = pk2((O[dt][nt][2] + Ob[2]) * inv,
                                (O[dt][nt][3] + Ob[3]) * inv);
                *(u16x4*)(op + dt * 16 + quad * 4) = pku.v;
            }
        }
    }
}

extern "C" void kernel_launch(void* const* d_in, const int* in_sizes, int n_in,
                              void* d_out, int out_size, void* d_ws, size_t ws_size,
                              hipStream_t stream) {
    (void)in_sizes; (void)n_in; (void)out_size;
    const float* Q  = (const float*)d_in[0];
    const float* K  = (const float*)d_in[1];
    const float* V  = (const float*)d_in[2];
    const float* Wq = (const float*)d_in[3];
    const float* bq = (const float*)d_in[4];
    const float* Wk = (const float*)d_in[5];
    const float* bk = (const float*)d_in[6];
    const float* Wv = (const float*)d_in[7];
    const float* bv = (const float*)d_in[8];
    const float* Wo = (const float*)d_in[9];
    const float* bo = (const float*)d_in[10];

    const size_t NEL = (size_t)2 * NH * SEQ * DH;  // 4,194,304 elements
    u16* base = (u16*)d_ws;
    dim3 bb(256);
    dim3 ab(512);

    if (ws_size >= 8 * NEL * 2) {
        u16* Qb   = base;
        u16* Kb   = Qb + NEL;
        u16* Vb   = Kb + NEL;
        u16* Wb   = Vb + NEL;
        u16* qws  = Wb + NEL;
        u16* kws  = qws + NEL;
        u16* vtws = kws + NEL;
        u16* aws  = vtws + NEL;
        cvt_all<<<dim3(2048, 7), bb, 0, stream>>>(Q, K, V, Wq, Wk, Wv, Wo, Qb, Kb, Vb, Wb);
        gemm_qkv_bb<<<dim3(8, 32, 3), bb, 0, stream>>>(
            Qb, Kb, Vb, Wb, bq, bk, bv, qws, kws, vtws);
        attn_kernel<<<dim3(SEQ / 128, 2 * NH), ab, 0, stream>>>(qws, kws, vtws, aws);
        gemm_o_p<<<dim3(16, 32), bb, 0, stream>>>(aws, Wb + 3145728, bo, (float*)d_out);
    } else if (ws_size >= 5 * NEL * 2) {
        u16* Wb = base;
        u16* qws = base + NEL; u16* kws = qws + NEL; u16* vtws = kws + NEL; u16* aws = vtws + NEL;
        cvt_w<<<dim3(512, 4), bb, 0, stream>>>(Wq, Wk, Wv, Wo, Wb);
        gemm_qkv<true><<<dim3(8, 32, 3), bb, 0, stream>>>(
            Q, K, V, Wb, Wb + 1048576, Wb + 2097152, bq, bk, bv, qws, kws, vtws);
        attn_kernel<<<dim3(SEQ / 128, 2 * NH), ab, 0, stream>>>(qws, kws, vtws, aws);
        gemm_o_p<<<dim3(16, 32), bb, 0, stream>>>(aws, Wb + 3145728, bo, (float*)d_out);
    } else {
        u16* qws = base; u16* kws = qws + NEL; u16* vtws = kws + NEL; u16* aws = vtws + NEL;
        gemm_qkv<false><<<dim3(8, 32, 3), bb, 0, stream>>>(
            Q, K, V, Wq, Wk, Wv, bq, bk, bv, qws, kws, vtws);
        attn_kernel<<<dim3(SEQ / 128, 2 * NH), ab, 0, stream>>>(qws, kws, vtws, aws);
        gemm_o<false><<<dim3(16, 32), bb, 0, stream>>>(aws, Wo, bo, (float*)d_out);
    }
}

// Round 17
// 206.097 us; speedup vs baseline: 1.0610x; 1.0610x over previous
//
#include <hip/hip_runtime.h>

#define SEQ 2048
#define DMODEL 1024
#define NH 16
#define DH 64

typedef __attribute__((ext_vector_type(8))) short bf16x8;
typedef __attribute__((ext_vector_type(4))) short bf16x4;
typedef __attribute__((ext_vector_type(4))) float floatx4;
typedef __attribute__((ext_vector_type(4))) unsigned short u16x4;
typedef unsigned short u16;
typedef unsigned int u32;

typedef const void __attribute__((address_space(1)))* as1cvp;
typedef void __attribute__((address_space(3)))* as3vp;

__device__ __forceinline__ void glds16(const void* g, void* l) {
    __builtin_amdgcn_global_load_lds((as1cvp)g, (as3vp)l, 16, 0, 0);
}

// f32->bf16 round-half-up: u + 0x8000, take hi16. Same 0.5-ulp worst case as
// RNE (only exact-tie direction differs -> unbiased for continuous data).
__device__ __forceinline__ u16 f2bf(float f) {
    union { u32 u; float f; } v; v.f = f;
    return (u16)((v.u + 0x8000u) >> 16);
}

// packed f32->2xbf16 half-up: 2 adds + 1 v_perm_b32 (hi16 of each)
__device__ __forceinline__ u32 pk2(float a, float b) {
    union { u32 u; float f; } x, y; x.f = a; y.f = b;
    u32 xr = x.u + 0x8000u, yr = y.u + 0x8000u;
#if __has_builtin(__builtin_amdgcn_perm)
    return __builtin_amdgcn_perm(yr, xr, 0x07060302u);
#else
    return (xr >> 16) | (yr & 0xffff0000u);
#endif
}

// raw v_exp_f32 (= exp2); log2e folded into QSCALE so scores are log2-domain.
__device__ __forceinline__ float ex2(float x) {
#if __has_builtin(__builtin_amdgcn_exp2f)
    return __builtin_amdgcn_exp2f(x);
#else
    float r; asm("v_exp_f32 %0, %1" : "=v"(r) : "v"(x)); return r;
#endif
}

__device__ __forceinline__ floatx4 mfma32(bf16x8 a, bf16x8 b, floatx4 c) {
    return __builtin_amdgcn_mfma_f32_16x16x32_bf16(a, b, c, 0, 0, 0);
}

__device__ __forceinline__ uint4 cvt8(const float* __restrict__ p) {
    float4 a = *(const float4*)p;
    float4 b = *(const float4*)(p + 4);
    uint4 q;
    q.x = pk2(a.x, a.y); q.y = pk2(a.z, a.w);
    q.z = pk2(b.x, b.y); q.w = pk2(b.z, b.w);
    return q;
}

// q pre-scale: 1/sqrt(Dh) * log2(e) -> scores are log2-domain, exp via v_exp_f32
#define QSCALE 0.18033688011112042f

// ---------------- convert Q,K,V + 4 weights to bf16 once ----------------
__global__ __launch_bounds__(256) void cvt_all(
    const float* __restrict__ Q, const float* __restrict__ K, const float* __restrict__ V,
    const float* __restrict__ W0, const float* __restrict__ W1,
    const float* __restrict__ W2, const float* __restrict__ W3,
    u16* __restrict__ Qb, u16* __restrict__ Kb, u16* __restrict__ Vb,
    u16* __restrict__ Wb)
{
    const int y = blockIdx.y;
    const float* src; u16* dst;
    if (y == 0)      { src = Q;  dst = Qb; }
    else if (y == 1) { src = K;  dst = Kb; }
    else if (y == 2) { src = V;  dst = Vb; }
    else {
        if (blockIdx.x >= 512) return;
        src = (y == 3) ? W0 : (y == 4) ? W1 : (y == 5) ? W2 : W3;
        dst = Wb + (size_t)(y - 3) * 1048576;
    }
    size_t i = ((size_t)blockIdx.x * 256 + threadIdx.x) * 8;
    *(uint4*)(dst + i) = cvt8(src + i);
}

__global__ __launch_bounds__(256) void cvt_w(
    const float* __restrict__ W0, const float* __restrict__ W1,
    const float* __restrict__ W2, const float* __restrict__ W3,
    u16* __restrict__ out)
{
    const float* src = (blockIdx.y == 0) ? W0 : (blockIdx.y == 1) ? W1
                     : (blockIdx.y == 2) ? W2 : W3;
    size_t i = ((size_t)blockIdx.x * 256 + threadIdx.x) * 8;
    *(uint4*)(out + (size_t)blockIdx.y * 1048576 + i) = cvt8(src + i);
}

// shared epilogue store for QKV projections (z<2: scalar, z=2: vectorized 8B)
__device__ __forceinline__ void qkv_store(
    int z, u16* __restrict__ outp, int rowg, int col, floatx4 a4, float bv, float sc)
{
    union { u32 w[2]; u16 h[4]; u16x4 v4; } pk;
    pk.w[0] = pk2((a4[0] + bv) * sc, (a4[1] + bv) * sc);
    pk.w[1] = pk2((a4[2] + bv) * sc, (a4[3] + bv) * sc);
    int b = rowg >> 11, s = rowg & 2047, h = col >> 6, d = col & 63;
    if (z < 2) {
#pragma unroll
        for (int r = 0; r < 4; r++)
            outp[((size_t)(b * NH + h) * SEQ + s + r) * DH + d] = pk.h[r];
    } else {
        *(u16x4*)(outp + ((size_t)(b * NH + h) * DH + d) * SEQ + s) = pk.v4;
    }
}

// ---------------- QKV projection: 3-buffer LDS pipeline, counted vmcnt ----------------
// XCD swizzle (T1): grid 768 blocks; each XCD gets 96 contiguous logical
// blocks (~12 A-panels x 8 bn in one z): A 3MB + W 2MB ~ L2-resident.
__global__ __launch_bounds__(256) void gemm_qkv_bb(
    const u16* __restrict__ Qb, const u16* __restrict__ Kb, const u16* __restrict__ Vb,
    const u16* __restrict__ Wb,
    const float* __restrict__ b0, const float* __restrict__ b1, const float* __restrict__ b2,
    u16* __restrict__ qo, u16* __restrict__ ko, u16* __restrict__ vto)
{
    __shared__ __align__(16) u16 As[3][4096];
    __shared__ __align__(16) u16 Bs[3][4096];
    const int tid = threadIdx.x, l = tid & 63, w = tid >> 6;
    const int lm = l & 15, quad = l >> 4;
    const int wr = (w >> 1) * 64, wc = (w & 1) * 64;
    const int orig = blockIdx.x + 8 * blockIdx.y + 256 * blockIdx.z;  // 0..767
    const int swz  = (orig & 7) * 96 + (orig >> 3);                   // bijective
    const int z    = swz >> 8;           // 0..2
    const int rem  = swz & 255;
    const int bm = (rem >> 3) * 128, bn = (rem & 7) * 128;
    const u16* A      = (z == 0) ? Qb : (z == 1) ? Kb : Vb;
    const u16* W      = Wb + (size_t)z * 1048576;
    const float* bias = (z == 0) ? b0 : (z == 1) ? b1 : b2;

    const int srow = tid >> 2, scol = (tid & 3) * 8;

    floatx4 acc[4][4];
#pragma unroll
    for (int i = 0; i < 4; i++)
#pragma unroll
        for (int j = 0; j < 4; j++) acc[i][j] = (floatx4){0.f, 0.f, 0.f, 0.f};

#define QKV_STAGE(I, NB) do { \
        const int kt_ = (I) * 32; \
        glds16(A + (size_t)(bm + srow) * DMODEL + kt_ + scol, As[NB] + w * 512); \
        glds16(A + (size_t)(bm + 64 + srow) * DMODEL + kt_ + scol, As[NB] + 2048 + w * 512); \
        glds16(W + (size_t)(bn + srow) * DMODEL + kt_ + scol, Bs[NB] + w * 512); \
        glds16(W + (size_t)(bn + 64 + srow) * DMODEL + kt_ + scol, Bs[NB] + 2048 + w * 512); \
    } while (0)

    QKV_STAGE(0, 0);
    QKV_STAGE(1, 1);
    asm volatile("s_waitcnt vmcnt(4)" ::: "memory");   // tile 0 complete
    __builtin_amdgcn_s_barrier();

    int cur = 0, nx = 2;
    for (int i = 0; i < 32; i++) {
        bf16x8 af[4], bfr[4];
#pragma unroll
        for (int mi = 0; mi < 4; mi++)
            af[mi] = *(const bf16x8*)(As[cur] + (wr + mi * 16 + lm) * 32 + quad * 8);
#pragma unroll
        for (int ni = 0; ni < 4; ni++)
            bfr[ni] = *(const bf16x8*)(Bs[cur] + (wc + ni * 16 + lm) * 32 + quad * 8);
#pragma unroll
        for (int mi = 0; mi < 4; mi++)
#pragma unroll
            for (int ni = 0; ni < 4; ni++)
                acc[mi][ni] = __builtin_amdgcn_mfma_f32_16x16x32_bf16(
                    af[mi], bfr[ni], acc[mi][ni], 0, 0, 0);

        if (i + 2 < 32) {
            QKV_STAGE(i + 2, nx);
            asm volatile("s_waitcnt vmcnt(4)" ::: "memory");  // tile i+1 done
            __builtin_amdgcn_s_barrier();
        } else if (i + 1 < 32) {
            asm volatile("s_waitcnt vmcnt(0)" ::: "memory");
            __builtin_amdgcn_s_barrier();
        }
        cur = (cur == 2) ? 0 : cur + 1;
        nx  = (nx == 2) ? 0 : nx + 1;
    }
#undef QKV_STAGE

    const float sc = (z == 0) ? QSCALE : 1.0f;
    u16* outp = (z == 0) ? qo : (z == 1) ? ko : vto;
#pragma unroll
    for (int ni = 0; ni < 4; ni++) {
        int col = bn + wc + ni * 16 + lm;
        float bv = bias[col];
#pragma unroll
        for (int mi = 0; mi < 4; mi++)
            qkv_store(z, outp, bm + wr + mi * 16 + quad * 4, col, acc[mi][ni], bv, sc);
    }
}

// ---------------- legacy QKV (A f32 converted in staging; fallback paths) ----------------
template<bool WBF>
__global__ __launch_bounds__(256) void gemm_qkv(
    const float* __restrict__ Qf, const float* __restrict__ Kf, const float* __restrict__ Vf,
    const void* __restrict__ W0, const void* __restrict__ W1, const void* __restrict__ W2,
    const float* __restrict__ b0, const float* __restrict__ b1, const float* __restrict__ b2,
    u16* __restrict__ qo, u16* __restrict__ ko, u16* __restrict__ vto)
{
    __shared__ __align__(16) u16 As[128 * 32];
    __shared__ __align__(16) u16 Bs[128 * 32];
    const int tid = threadIdx.x, l = tid & 63, w = tid >> 6;
    const int lm = l & 15, quad = l >> 4;
    const int wr = (w >> 1) * 64, wc = (w & 1) * 64;
    const int bm = blockIdx.y * 128, bn = blockIdx.x * 128;
    const int z = blockIdx.z;
    const float* A    = (z == 0) ? Qf : (z == 1) ? Kf : Vf;
    const void* Wp    = (z == 0) ? W0 : (z == 1) ? W1 : W2;
    const float* bias = (z == 0) ? b0 : (z == 1) ? b1 : b2;

    floatx4 acc[4][4];
#pragma unroll
    for (int i = 0; i < 4; i++)
#pragma unroll
        for (int j = 0; j < 4; j++) acc[i][j] = (floatx4){0.f, 0.f, 0.f, 0.f};

    for (int kt = 0; kt < DMODEL; kt += 32) {
        __syncthreads();
#pragma unroll
        for (int j = 0; j < 2; j++) {
            int ch = j * 256 + tid, row = ch >> 2, c = ch & 3;
            *(uint4*)(As + ch * 8) = cvt8(A + (size_t)(bm + row) * DMODEL + kt + c * 8);
        }
        if (WBF) {
            const u16* Wc = (const u16*)Wp;
            glds16(Wc + (size_t)(bn + (tid >> 2)) * DMODEL + kt + (tid & 3) * 8, Bs + w * 512);
            glds16(Wc + (size_t)(bn + 64 + (tid >> 2)) * DMODEL + kt + (tid & 3) * 8, Bs + 2048 + w * 512);
        } else {
            const float* Wf = (const float*)Wp;
#pragma unroll
            for (int j = 0; j < 2; j++) {
                int ch = j * 256 + tid, row = ch >> 2, c = ch & 3;
                *(uint4*)(Bs + ch * 8) = cvt8(Wf + (size_t)(bn + row) * DMODEL + kt + c * 8);
            }
        }
        __syncthreads();

        bf16x8 af[4], bfr[4];
#pragma unroll
        for (int mi = 0; mi < 4; mi++)
            af[mi] = *(const bf16x8*)(As + (wr + mi * 16 + lm) * 32 + quad * 8);
#pragma unroll
        for (int ni = 0; ni < 4; ni++)
            bfr[ni] = *(const bf16x8*)(Bs + (wc + ni * 16 + lm) * 32 + quad * 8);
#pragma unroll
        for (int mi = 0; mi < 4; mi++)
#pragma unroll
            for (int ni = 0; ni < 4; ni++)
                acc[mi][ni] = __builtin_amdgcn_mfma_f32_16x16x32_bf16(
                    af[mi], bfr[ni], acc[mi][ni], 0, 0, 0);
    }

    const float sc = (z == 0) ? QSCALE : 1.0f;
    u16* outp = (z == 0) ? qo : (z == 1) ? ko : vto;
#pragma unroll
    for (int ni = 0; ni < 4; ni++) {
        int col = bn + wc + ni * 16 + lm;
        float bv = bias[col];
#pragma unroll
        for (int mi = 0; mi < 4; mi++)
            qkv_store(z, outp, bm + wr + mi * 16 + quad * 4, col, acc[mi][ni], bv, sc);
    }
}

// ---------------- O-projection (bf16 W): 3-buffer pipeline, counted vmcnt ----------------
// XCD swizzle (T1): 512 blocks; each XCD owns 64 contiguous logical blocks.
__global__ __launch_bounds__(256) void gemm_o_p(
    const u16* __restrict__ A, const u16* __restrict__ W,
    const float* __restrict__ bias, float* __restrict__ out)
{
    __shared__ __align__(16) u16 As[3][4096];
    __shared__ __align__(16) u16 Bs[3][2048];
    const int tid = threadIdx.x, l = tid & 63, w = tid >> 6;
    const int lm = l & 15, quad = l >> 4;
    const int orig = blockIdx.x + 16 * blockIdx.y;          // 0..511
    const int swz  = (orig & 7) * 64 + (orig >> 3);         // bijective
    const int bm = (swz >> 4) * 128, bn = (swz & 15) * 64;

    floatx4 acc[2][4];
#pragma unroll
    for (int i = 0; i < 2; i++)
#pragma unroll
        for (int j = 0; j < 4; j++) acc[i][j] = (floatx4){0.f, 0.f, 0.f, 0.f};

#define O_STAGE(I, NB) do { \
        const int kt_ = (I) * 32; \
        glds16(A + (size_t)(bm + (tid >> 2)) * DMODEL + kt_ + (tid & 3) * 8, As[NB] + w * 512); \
        glds16(A + (size_t)(bm + 64 + (tid >> 2)) * DMODEL + kt_ + (tid & 3) * 8, As[NB] + 2048 + w * 512); \
        glds16(W + (size_t)(bn + (tid >> 2)) * DMODEL + kt_ + (tid & 3) * 8, Bs[NB] + w * 512); \
    } while (0)

    O_STAGE(0, 0);
    O_STAGE(1, 1);
    asm volatile("s_waitcnt vmcnt(3)" ::: "memory");
    __builtin_amdgcn_s_barrier();

    int cur = 0, nx = 2;
    for (int i = 0; i < 32; i++) {
        bf16x8 af[2], bfr[4];
#pragma unroll
        for (int mi = 0; mi < 2; mi++)
            af[mi] = *(const bf16x8*)(As[cur] + (w * 32 + mi * 16 + lm) * 32 + quad * 8);
#pragma unroll
        for (int ni = 0; ni < 4; ni++)
            bfr[ni] = *(const bf16x8*)(Bs[cur] + (ni * 16 + lm) * 32 + quad * 8);
#pragma unroll
        for (int mi = 0; mi < 2; mi++)
#pragma unroll
            for (int ni = 0; ni < 4; ni++)
                acc[mi][ni] = __builtin_amdgcn_mfma_f32_16x16x32_bf16(
                    af[mi], bfr[ni], acc[mi][ni], 0, 0, 0);

        if (i + 2 < 32) {
            O_STAGE(i + 2, nx);
            asm volatile("s_waitcnt vmcnt(3)" ::: "memory");
            __builtin_amdgcn_s_barrier();
        } else if (i + 1 < 32) {
            asm volatile("s_waitcnt vmcnt(0)" ::: "memory");
            __builtin_amdgcn_s_barrier();
        }
        cur = (cur == 2) ? 0 : cur + 1;
        nx  = (nx == 2) ? 0 : nx + 1;
    }
#undef O_STAGE

#pragma unroll
    for (int ni = 0; ni < 4; ni++) {
        int col = bn + ni * 16 + lm;
        float bv = bias[col];
#pragma unroll
        for (int mi = 0; mi < 2; mi++) {
#pragma unroll
            for (int r = 0; r < 4; r++) {
                int rowg = bm + w * 32 + mi * 16 + quad * 4 + r;
                out[(size_t)rowg * DMODEL + col] = acc[mi][ni][r] + bv;
            }
        }
    }
}

// ---------------- legacy O-projection (f32 W fallback) ----------------
template<bool WBF>
__global__ __launch_bounds__(256) void gemm_o(
    const u16* __restrict__ A, const void* __restrict__ Wp,
    const float* __restrict__ bias, float* __restrict__ out)
{
    __shared__ __align__(16) u16 As[128 * 32];
    __shared__ __align__(16) u16 Bs[64 * 32];
    const int tid = threadIdx.x, l = tid & 63, w = tid >> 6;
    const int lm = l & 15, quad = l >> 4;
    const int bm = blockIdx.y * 128, bn = blockIdx.x * 64;

    floatx4 acc[2][4];
#pragma unroll
    for (int i = 0; i < 2; i++)
#pragma unroll
        for (int j = 0; j < 4; j++) acc[i][j] = (floatx4){0.f, 0.f, 0.f, 0.f};

    for (int kt = 0; kt < DMODEL; kt += 32) {
        __syncthreads();
        glds16(A + (size_t)(bm + (tid >> 2)) * DMODEL + kt + (tid & 3) * 8, As + w * 512);
        glds16(A + (size_t)(bm + 64 + (tid >> 2)) * DMODEL + kt + (tid & 3) * 8, As + 2048 + w * 512);
        if (WBF) {
            glds16((const u16*)Wp + (size_t)(bn + (tid >> 2)) * DMODEL + kt + (tid & 3) * 8, Bs + w * 512);
        } else {
            *(uint4*)(Bs + tid * 8) =
                cvt8((const float*)Wp + (size_t)(bn + (tid >> 2)) * DMODEL + kt + (tid & 3) * 8);
        }
        __syncthreads();

        bf16x8 af[2], bfr[4];
#pragma unroll
        for (int mi = 0; mi < 2; mi++)
            af[mi] = *(const bf16x8*)(As + (w * 32 + mi * 16 + lm) * 32 + quad * 8);
#pragma unroll
        for (int ni = 0; ni < 4; ni++)
            bfr[ni] = *(const bf16x8*)(Bs + (ni * 16 + lm) * 32 + quad * 8);
#pragma unroll
        for (int mi = 0; mi < 2; mi++)
#pragma unroll
            for (int ni = 0; ni < 4; ni++)
                acc[mi][ni] = __builtin_amdgcn_mfma_f32_16x16x32_bf16(
                    af[mi], bfr[ni], acc[mi][ni], 0, 0, 0);
    }

#pragma unroll
    for (int ni = 0; ni < 4; ni++) {
        int col = bn + ni * 16 + lm;
        float bv = bias[col];
#pragma unroll
        for (int mi = 0; mi < 2; mi++) {
#pragma unroll
            for (int r = 0; r < 4; r++) {
                int rowg = bm + w * 32 + mi * 16 + quad * 4 + r;
                out[(size_t)rowg * DMODEL + col] = acc[mi][ni][r] + bv;
            }
        }
    }
}

// ---------------- Flash attention v15 (r15-verified, 43.2us): 8 waves x 32 q-rows ----------------
// Best verified attn. r16's deferred-PV regressed (2nd barrier convoy +
// concentrated LDS phase: occupancy 29->19, 54us) -> T15 retired for this
// kernel. Structure: wave w = q-group rg=w&3 (32 rows, 2 nt) x key-half w>>2;
// full-rate PV via permuted-K staging; no-max log2-domain softmax;
// l-via-ones-MFMA; double-buffer + mid-loop staging + raw barriers;
// T1 XCD swizzle; ~108 VGPR under the (512,2) 128 cap.
#define SP 72
#define TS (64 * SP)          // one K or V tile in u16
#define BUFSZ (4 * TS)        // [K0][K1][V0][V1]
__global__ __launch_bounds__(512, 2) void attn_kernel(
    const u16* __restrict__ q, const u16* __restrict__ k,
    const u16* __restrict__ vt, u16* __restrict__ out)
{
    __shared__ __align__(16) u16 smem[2 * BUFSZ];   // 73728 B
    const int tid = threadIdx.x, l = tid & 63, w = tid >> 6;   // w in 0..7
    const int lm = l & 15, quad = l >> 4;
    // XCD-aware swizzle (T1): each XCD owns 64 contiguous logical blocks.
    const int orig = blockIdx.x + 16 * blockIdx.y;          // 0..511
    const int swz  = (orig & 7) * 64 + (orig >> 3);         // bijective
    const int qt = swz & 15, bh = swz >> 4;
    const int b = bh >> 4, h = bh & 15;
    const int rg = w & 3, half = w >> 2;

    bf16x8 qf[2][2];
#pragma unroll
    for (int nt = 0; nt < 2; nt++) {
        int row = qt * 128 + rg * 32 + nt * 16 + lm;
        const u16* qp = q + ((size_t)bh * SEQ + row) * DH;
        qf[nt][0] = *(const bf16x8*)(qp + quad * 8);
        qf[nt][1] = *(const bf16x8*)(qp + 32 + quad * 8);
    }

    floatx4 O[4][2];
#pragma unroll
    for (int dt = 0; dt < 4; dt++)
#pragma unroll
        for (int nt = 0; nt < 2; nt++) O[dt][nt] = (floatx4){0.f, 0.f, 0.f, 0.f};
    floatx4 Ol[2] = {(floatx4){0.f,0.f,0.f,0.f}, (floatx4){0.f,0.f,0.f,0.f}};

    const bf16x8 ones8 = {(short)0x3F80, (short)0x3F80, (short)0x3F80, (short)0x3F80,
                          (short)0x3F80, (short)0x3F80, (short)0x3F80, (short)0x3F80};

    // staging: 512 threads; K: key srow = tid>>3 (0..63), chunk sc = tid&7
    // (8 x 16B = 64 d). V: d = srow, keys chunk sc. One uint4 each per half.
    const int srow = tid >> 3, sc = tid & 7;
    // permuted K row: key srow = p*32+q*8+s*4+r -> row p*32+s*16+q*4+r
    const int prow = (srow & 32) | ((srow & 4) << 2) | ((srow & 24) >> 1) | (srow & 3);
    const u16* kbase = k + (size_t)bh * SEQ * DH;
    const u16* vbase = vt + (size_t)bh * DH * SEQ;

    uint4 kA, kB, vA, vB;
#define LOADT(T) do { \
        kA = *(const uint4*)(kbase + (size_t)((T) * 64 + srow) * DH + sc * 8); \
        kB = *(const uint4*)(kbase + (size_t)(1024 + (T) * 64 + srow) * DH + sc * 8); \
        vA = *(const uint4*)(vbase + (size_t)srow * SEQ + (T) * 64 + sc * 8); \
        vB = *(const uint4*)(vbase + (size_t)srow * SEQ + 1024 + (T) * 64 + sc * 8); \
    } while (0)
#define WRBUF(BUF) do { \
        u16* K0 = smem + (BUF) * BUFSZ; \
        u16* K1 = K0 + TS; \
        u16* V0 = K0 + 2 * TS; \
        u16* V1 = K0 + 3 * TS; \
        *(uint4*)(K0 + prow * SP + sc * 8) = kA; \
        *(uint4*)(K1 + prow * SP + sc * 8) = kB; \
        *(uint4*)(V0 + srow * SP + sc * 8) = vA; \
        *(uint4*)(V1 + srow * SP + sc * 8) = vB; \
    } while (0)

    LOADT(0);
    WRBUF(0);
    LOADT(1);
    asm volatile("s_waitcnt lgkmcnt(0)" ::: "memory");
    __builtin_amdgcn_s_barrier();

    for (int t = 0; t < 16; t++) {
        const int cur = t & 1;
        const u16* Kh = smem + cur * BUFSZ + half * TS;
        const u16* Vh = smem + cur * BUFSZ + (2 + half) * TS;

        // QK + exp per p-pair (Sc transient: 4 floatx4 live, not 8)
        bf16x8 pbm[2][2];
#pragma unroll
        for (int p = 0; p < 2; p++) {
            floatx4 Sc0[2], Sc1[2];
            __builtin_amdgcn_s_setprio(1);
#pragma unroll
            for (int s = 0; s < 2; s++) {
                const int sub = p * 2 + s;
                bf16x8 ka0 = *(const bf16x8*)(Kh + (sub * 16 + lm) * SP + quad * 8);
                bf16x8 ka1 = *(const bf16x8*)(Kh + (sub * 16 + lm) * SP + 32 + quad * 8);
#pragma unroll
                for (int nt = 0; nt < 2; nt++) {
                    floatx4 c = (floatx4){0.f, 0.f, 0.f, 0.f};
                    c = mfma32(ka0, qf[nt][0], c);
                    c = mfma32(ka1, qf[nt][1], c);
                    if (s == 0) Sc0[nt] = c; else Sc1[nt] = c;
                }
            }
            __builtin_amdgcn_s_setprio(0);
#pragma unroll
            for (int nt = 0; nt < 2; nt++) {
                floatx4 sa = Sc0[nt], sb = Sc1[nt];
#pragma unroll
                for (int r = 0; r < 4; r++) { sa[r] = ex2(sa[r]); sb[r] = ex2(sb[r]); }
                union { u32 w4[4]; bf16x8 v; } pku;
                pku.w4[0] = pk2(sa[0], sa[1]);
                pku.w4[1] = pk2(sa[2], sa[3]);
                pku.w4[2] = pk2(sb[0], sb[1]);
                pku.w4[3] = pk2(sb[2], sb[3]);
                pbm[p][nt] = pku.v;
            }
        }

        // mid-loop staging: drain t+1 loads, write idle buffer, launch t+2.
        if (t + 1 < 16) {
            asm volatile("s_waitcnt vmcnt(0)" ::: "memory");
            WRBUF(cur ^ 1);
            if (t + 2 < 16) LOADT(t + 2);
        }

        __builtin_amdgcn_s_setprio(1);
        // l += colsum(P) via all-ones A-frag, full-rate x32 (C col lm = q-row)
#pragma unroll
        for (int nt = 0; nt < 2; nt++) {
            Ol[nt] = mfma32(ones8, pbm[0][nt], Ol[nt]);
            Ol[nt] = mfma32(ones8, pbm[1][nt], Ol[nt]);
        }

        // O^T += V^T·P^T, full-rate x32: A = linear V^T rows (k = key)
#pragma unroll
        for (int dt = 0; dt < 4; dt++) {
            bf16x8 va0 = *(const bf16x8*)(Vh + (dt * 16 + lm) * SP + quad * 8);
            bf16x8 va1 = *(const bf16x8*)(Vh + (dt * 16 + lm) * SP + 32 + quad * 8);
#pragma unroll
            for (int nt = 0; nt < 2; nt++) {
                O[dt][nt] = mfma32(va0, pbm[0][nt], O[dt][nt]);
                O[dt][nt] = mfma32(va1, pbm[1][nt], O[dt][nt]);
            }
        }
        __builtin_amdgcn_s_setprio(0);

        // one barrier per tile: WRBUF writes + frag reads all drained by lgkm
        asm volatile("s_waitcnt lgkmcnt(0)" ::: "memory");
        __builtin_amdgcn_s_barrier();
    }
#undef LOADT
#undef WRBUF

    // ---- in-block merge of the two key-halves through LDS (f32) ----
    // no-max: O = (O_A + O_B) / (l_A + l_B). Stride 36 floats (144B,
    // 16B-aligned, 4-bank row shift -> 8-way on b128, acceptable once).
    float* obuf  = (float*)smem;           // [4 rg][64 lane][36] = 36864B
    float* mlbuf = (float*)smem + 9216;    // [4 rg][64 lane][2]  =  2048B
    if (half == 1) {
        float* ob = obuf + (rg * 64 + l) * 36;
        float* ml = mlbuf + (rg * 64 + l) * 2;
#pragma unroll
        for (int nt = 0; nt < 2; nt++) {
#pragma unroll
            for (int dt = 0; dt < 4; dt++)
                *(floatx4*)(ob + nt * 16 + dt * 4) = O[dt][nt];
            ml[nt] = Ol[nt][0];
        }
    }
    __syncthreads();
    if (half == 0) {
        float* ob = obuf + (rg * 64 + l) * 36;
        float* ml = mlbuf + (rg * 64 + l) * 2;
#pragma unroll
        for (int nt = 0; nt < 2; nt++) {
            float lB = ml[nt];
            float inv = 1.0f / (Ol[nt][0] + lB);
            int s = qt * 128 + rg * 32 + nt * 16 + lm;
            u16* op = out + ((size_t)b * SEQ + s) * DMODEL + h * DH;
#pragma unroll
            for (int dt = 0; dt < 4; dt++) {
                floatx4 Ob = *(const floatx4*)(ob + nt * 16 + dt * 4);
                union { u32 w2[2]; u16x4 v; } pku;
                pku.w2[0] = pk2((O[dt][nt][0] + Ob[0]) * inv,
                                (O[dt][nt][1] + Ob[1]) * inv);
                pku.w2[1] = pk2((O[dt][nt][2] + Ob[2]) * inv,
                                (O[dt][nt][3] + Ob[3]) * inv);
                *(u16x4*)(op + dt * 16 + quad * 4) = pku.v;
            }
        }
    }
}

extern "C" void kernel_launch(void* const* d_in, const int* in_sizes, int n_in,
                              void* d_out, int out_size, void* d_ws, size_t ws_size,
                              hipStream_t stream) {
    (void)in_sizes; (void)n_in; (void)out_size;
    const float* Q  = (const float*)d_in[0];
    const float* K  = (const float*)d_in[1];
    const float* V  = (const float*)d_in[2];
    const float* Wq = (const float*)d_in[3];
    const float* bq = (const float*)d_in[4];
    const float* Wk = (const float*)d_in[5];
    const float* bk = (const float*)d_in[6];
    const float* Wv = (const float*)d_in[7];
    const float* bv = (const float*)d_in[8];
    const float* Wo = (const float*)d_in[9];
    const float* bo = (const float*)d_in[10];

    const size_t NEL = (size_t)2 * NH * SEQ * DH;  // 4,194,304 elements
    u16* base = (u16*)d_ws;
    dim3 bb(256);
    dim3 ab(512);

    if (ws_size >= 8 * NEL * 2) {
        u16* Qb   = base;
        u16* Kb   = Qb + NEL;
        u16* Vb   = Kb + NEL;
        u16* Wb   = Vb + NEL;
        u16* qws  = Wb + NEL;
        u16* kws  = qws + NEL;
        u16* vtws = kws + NEL;
        u16* aws  = vtws + NEL;
        cvt_all<<<dim3(2048, 7), bb, 0, stream>>>(Q, K, V, Wq, Wk, Wv, Wo, Qb, Kb, Vb, Wb);
        gemm_qkv_bb<<<dim3(8, 32, 3), bb, 0, stream>>>(
            Qb, Kb, Vb, Wb, bq, bk, bv, qws, kws, vtws);
        attn_kernel<<<dim3(SEQ / 128, 2 * NH), ab, 0, stream>>>(qws, kws, vtws, aws);
        gemm_o_p<<<dim3(16, 32), bb, 0, stream>>>(aws, Wb + 3145728, bo, (float*)d_out);
    } else if (ws_size >= 5 * NEL * 2) {
        u16* Wb = base;
        u16* qws = base + NEL; u16* kws = qws + NEL; u16* vtws = kws + NEL; u16* aws = vtws + NEL;
        cvt_w<<<dim3(512, 4), bb, 0, stream>>>(Wq, Wk, Wv, Wo, Wb);
        gemm_qkv<true><<<dim3(8, 32, 3), bb, 0, stream>>>(
            Q, K, V, Wb, Wb + 1048576, Wb + 2097152, bq, bk, bv, qws, kws, vtws);
        attn_kernel<<<dim3(SEQ / 128, 2 * NH), ab, 0, stream>>>(qws, kws, vtws, aws);
        gemm_o_p<<<dim3(16, 32), bb, 0, stream>>>(aws, Wb + 3145728, bo, (float*)d_out);
    } else {
        u16* qws = base; u16* kws = qws + NEL; u16* vtws = kws + NEL; u16* aws = vtws + NEL;
        gemm_qkv<false><<<dim3(8, 32, 3), bb, 0, stream>>>(
            Q, K, V, Wq, Wk, Wv, bq, bk, bv, qws, kws, vtws);
        attn_kernel<<<dim3(SEQ / 128, 2 * NH), ab, 0, stream>>>(qws, kws, vtws, aws);
        gemm_o<false><<<dim3(16, 32), bb, 0, stream>>>(aws, Wo, bo, (float*)d_out);
    }
}